// Round 13
// baseline (572.900 us; speedup 1.0000x reference)
//
#include <hip/hip_runtime.h>
#include <math.h>

typedef _Float16 f16;
typedef _Float16 f16x2 __attribute__((ext_vector_type(2)));
typedef _Float16 f16x8 __attribute__((ext_vector_type(8)));
typedef float f32x4 __attribute__((ext_vector_type(4)));
typedef unsigned long long u64;

#define LDIM 128
#define HOUT 256

// LDS (bytes):
//  h-panel  @ 0:      [34 rows][256 c] f16, row 512 B  -> 17408   (single plane, in-place per step)
//  x-panels @ 17408:  2 x { [2 planes][34 rows][128 c] f16 } -> 2 x 17408 (plane stride 8704)
// Row r <-> column W0 + r, W0 = l0 - 9. 16B-granule XOR swizzle: granule ^= (row & 7).
#define XP 17408

__device__ __forceinline__ float tanh_fast(float x) {
    float a = fabsf(x);
    float e = __expf(-2.0f * a);
    float r = (1.0f - e) / (1.0f + e);
    return copysignf(r, x);
}

__device__ __forceinline__ void st_mb(u64* p, u64 v) {
    __hip_atomic_store(p, v, __ATOMIC_RELAXED, __HIP_MEMORY_SCOPE_AGENT);
}
__device__ __forceinline__ u64 ld_mb(const u64* p) {
    return __hip_atomic_load(p, __ATOMIC_RELAXED, __HIP_MEMORY_SCOPE_AGENT);
}
__device__ __forceinline__ unsigned pack_h2(float a, float b) {
    f16x2 t; t[0] = (f16)a; t[1] = (f16)b;
    unsigned u; __builtin_memcpy(&u, &t, 4); return u;
}

// A-frag packings (f16) — unchanged from R12:
//  wt_i: [(((s*4+kk)*16+h16)*64+lane)*8+j] = W_i[h16*16+(lane&15)][kk*32+(lane>>4)*8+j][s]
//  wt_h: [(((s*8+kk)*16+h16)*64+lane)*8+j] = W_h[h16*16+(lane&15)][kk*32+(lane>>4)*8+j][s]
__global__ void prep_w(const float* __restrict__ wi, f16* __restrict__ wtif,
                       const float* __restrict__ wh, f16* __restrict__ wthf)
{
    int idx = blockIdx.x * 256 + threadIdx.x;
    const int ni = 3 * 4 * 16 * 64 * 8;      // 98304
    if (idx < ni) {
        int j    = idx & 7;
        int lane = (idx >> 3) & 63;
        int h16  = (idx >> 9) & 15;
        int kk   = (idx >> 13) & 3;
        int s    = idx >> 15;
        int h = h16 * 16 + (lane & 15);
        int c = kk * 32 + (lane >> 4) * 8 + j;
        wtif[idx] = (f16)wi[(h * 128 + c) * 3 + s];
    } else {
        int e = idx - ni;
        if (e >= 3 * 8 * 16 * 64 * 8) return;  // 196608
        int j    = e & 7;
        int lane = (e >> 3) & 63;
        int h16  = (e >> 9) & 15;
        int kk   = (e >> 13) & 7;
        int s    = e >> 16;
        int h = h16 * 16 + (lane & 15);
        int c = kk * 32 + (lane >> 4) * 8 + j;
        wthf[e] = (f16)wh[(h * 256 + c) * 3 + s];
    }
}

// stage x[b][t2][128 c][W0 .. W0+33] -> x-panel (hi/lo, swizzled). Chunk-granular range mask.
__device__ __forceinline__ void stage_x(char* xp, const float* __restrict__ xt,
                                        int l0, int tid)
{
    const int c = tid >> 2, q = tid & 3;
    const int colStart = l0 - 8 + q * 8;     // multiples of 8; chunk fully in or fully out
    f32x4 v0 = {}, v1 = {};
    if (colStart >= 0 && colStart + 7 < 128) {
        v0 = *(const f32x4*)(xt + c * LDIM + colStart);
        v1 = *(const f32x4*)(xt + c * LDIM + colStart + 4);
    }
#pragma unroll
    for (int i = 0; i < 8; ++i) {
        int row = q * 8 + i + 1;             // rows 1..32
        float xx = (i < 4) ? v0[i] : v1[i - 4];
        f16 h = (f16)xx, lo = (f16)(xx - (float)h);
        int off = row * 256 + ((((c >> 3) ^ (row & 7)) << 4)) + (c & 7) * 2;
        *(f16*)(xp + off) = h;
        *(f16*)(xp + 8704 + off) = lo;
    }
    if (tid < 256) {                         // edge rows 0 (col W0) and 33 (col W0+33)
        int row = (tid >= 128) ? 33 : 0;
        int cc  = tid & 127;
        int col = (row == 0) ? l0 - 9 : l0 + 24;
        float xx = ((unsigned)col < 128u) ? xt[cc * LDIM + col] : 0.f;
        f16 h = (f16)xx, lo = (f16)(xx - (float)h);
        int off = row * 256 + ((((cc >> 3) ^ (row & 7)) << 4)) + (cc & 7) * 2;
        *(f16*)(xp + off) = h;
        *(f16*)(xp + 8704 + off) = lo;
    }
}

// ---------------- Fused persistent kernel, ghost-zone time-tiled ----------------
// 128 blocks = 16 b x 8 windows; 512 thr = 8 waves; wave owns 32 h.
// Window: core [l0, l0+16) + 8-col ghost margins; computes 32 cols (2 MFMA tiles) every step.
// Cross-block exchange only every 8 steps (t = 8,16,...,56): 9-col core strips via
// self-timestamped mailbox (u64 = tag<<32 | 2 x f16), double-buffered by exchange parity.
__global__ void __launch_bounds__(512)
rnn_fused(const float* __restrict__ x, const f16* __restrict__ wti,
          const f16* __restrict__ wth, float* __restrict__ out,
          u64* __restrict__ mbox)
{
    __shared__ __align__(16) char smem[52224];
    const int tid  = threadIdx.x;
    const int lane = tid & 63, wid = tid >> 6;   // 8 waves
    const int b    = blockIdx.x & 15;
    const int lw   = blockIdx.x >> 4;            // 0..7
    const int l0   = lw * 16;
    const int l16  = lane & 15, g = lane >> 4;
    const long HL  = (long)HOUT * LDIM;
    float* outb    = out + (long)b * (64 * HL);
    const float* xb = x + (long)b * (64L * 128 * LDIM);

    // ---- prologue: zero h-panel rows 0/33; stage x[0] into buf0
    {
        int row = (tid >= 256) ? 33 : 0;
        int cc  = tid & 255;
        int off = row * 512 + ((((cc >> 3) ^ (row & 7)) << 4)) + (cc & 7) * 2;
        *(f16*)(smem + off) = (f16)0.f;
    }
    stage_x(smem + XP, xb, l0, tid);
    __syncthreads();

    for (int t = 0; t < 64; ++t) {
        float* outt = outb + (long)t * HL;

        // ---- stage x[t+1] into the other x-buffer
        if (t + 1 < 64)
            stage_x(smem + XP + ((t + 1) & 1) * 17408,
                    xb + (long)(t + 1) * (128 * LDIM), l0, tid);

        // ---- Z_t for both tiles from x-buffer (t&1)
        f32x4 zcur[2][2] = {};
        {
            const char* xp = smem + XP + (t & 1) * 17408;
#pragma unroll
            for (int kk = 0; kk < 4; ++kk)
#pragma unroll
                for (int s = 0; s < 3; ++s) {
                    f16x8 a0 = *(const f16x8*)(wti +
                        ((((s * 4 + kk) * 16 + wid * 2 + 0) * 64 + lane) << 3));
                    f16x8 a1 = *(const f16x8*)(wti +
                        ((((s * 4 + kk) * 16 + wid * 2 + 1) * 64 + lane) << 3));
#pragma unroll
                    for (int tau = 0; tau < 2; ++tau) {
                        int r = 16 * tau + l16 + s;
                        int base = r * 256 + ((((kk * 4 + g) ^ (r & 7)) << 4));
                        f16x8 bh = *(const f16x8*)(xp + base);
                        f16x8 bl = *(const f16x8*)(xp + 8704 + base);
                        zcur[tau][0] = __builtin_amdgcn_mfma_f32_16x16x32_f16(a0, bh, zcur[tau][0], 0, 0, 0);
                        zcur[tau][0] = __builtin_amdgcn_mfma_f32_16x16x32_f16(a0, bl, zcur[tau][0], 0, 0, 0);
                        zcur[tau][1] = __builtin_amdgcn_mfma_f32_16x16x32_f16(a1, bh, zcur[tau][1], 0, 0, 0);
                        zcur[tau][1] = __builtin_amdgcn_mfma_f32_16x16x32_f16(a1, bl, zcur[tau][1], 0, 0, 0);
                    }
                }
        }

        // ---- h-conv (h_{t-1} panel, in place), both tiles, A-frags streamed from L2
        f32x4 hacc[2][2] = {};
        if (t > 0) {
#pragma unroll
            for (int kk = 0; kk < 8; ++kk)
#pragma unroll
                for (int s = 0; s < 3; ++s) {
                    f16x8 a0 = *(const f16x8*)(wth +
                        ((((s * 8 + kk) * 16 + wid * 2 + 0) * 64 + lane) << 3));
                    f16x8 a1 = *(const f16x8*)(wth +
                        ((((s * 8 + kk) * 16 + wid * 2 + 1) * 64 + lane) << 3));
#pragma unroll
                    for (int tau = 0; tau < 2; ++tau) {
                        int r = 16 * tau + l16 + s;
                        int base = r * 512 + ((((kk * 4 + g) ^ (r & 7)) << 4));
                        f16x8 bb = *(const f16x8*)(smem + base);
                        hacc[tau][0] = __builtin_amdgcn_mfma_f32_16x16x32_f16(a0, bb, hacc[tau][0], 0, 0, 0);
                        hacc[tau][1] = __builtin_amdgcn_mfma_f32_16x16x32_f16(a1, bb, hacc[tau][1], 0, 0, 0);
                    }
                }
        }
        __syncthreads();   // all panel reads done before in-place rewrite

        // ---- epilogue: h_t = tanh(hacc + Z_t); out-store core; panel write (masked)
        float hv[2][2][4];
#pragma unroll
        for (int tau = 0; tau < 2; ++tau)
#pragma unroll
            for (int hf = 0; hf < 2; ++hf)
#pragma unroll
                for (int vv = 0; vv < 4; ++vv)
                    hv[tau][hf][vv] = tanh_fast(hacc[tau][hf][vv] + zcur[tau][hf][vv]);

        {   // out store: each thread's core column
            const int tsel = (l16 < 8) ? 1 : 0;
            const int gcs  = l0 + (l16 ^ 8);
#pragma unroll
            for (int hf = 0; hf < 2; ++hf)
#pragma unroll
                for (int vv = 0; vv < 4; ++vv) {
                    int c = wid * 32 + hf * 16 + g * 4 + vv;
                    outt[(long)c * LDIM + gcs] = hv[tsel][hf][vv];
                }
        }
#pragma unroll
        for (int tau = 0; tau < 2; ++tau) {
            const int rw = 1 + 16 * tau + l16;
            const int gc = l0 - 9 + rw;
            const bool ok = ((unsigned)gc < 128u);
            const int rx = rw & 7;
#pragma unroll
            for (int hf = 0; hf < 2; ++hf)
#pragma unroll
                for (int p = 0; p < 2; ++p) {
                    int c = wid * 32 + hf * 16 + g * 4 + p * 2;
                    f16x2 w;
                    w[0] = ok ? (f16)hv[tau][hf][2 * p]     : (f16)0.f;
                    w[1] = ok ? (f16)hv[tau][hf][2 * p + 1] : (f16)0.f;
                    int off = rw * 512 + ((((c >> 3) ^ rx) << 4)) + (c & 7) * 2;
                    *(f16x2*)(smem + off) = w;
                }
        }
        __syncthreads();   // h_t panel complete

        // ---- exchange every 8 steps: publish 9-col core strips, refill margins
        if (t > 0 && (t & 7) == 0 && t <= 56) {
            const unsigned e = (unsigned)(t >> 3);       // 1..7
            const int par = e & 1;
            const u64 tagw = ((u64)e) << 32;

            // publish left strip (cols l0..l0+8, read by left neighbor)
            {
                int cs = -1, tl = 0;
                if (l16 >= 8)      { cs = l16 - 8; tl = 0; }
                else if (l16 == 0) { cs = 8;       tl = 1; }
                if (cs >= 0 && lw > 0) {
                    u64* mp = mbox + (((long)(b * 8 + lw) * 2 + 0) * 2 + par) * 1152 + cs * 128;
#pragma unroll
                    for (int hf = 0; hf < 2; ++hf)
#pragma unroll
                        for (int p = 0; p < 2; ++p) {
                            int hp = wid * 16 + hf * 8 + g * 2 + p;
                            st_mb(mp + hp, tagw |
                                  (u64)pack_h2(hv[tl][hf][2 * p], hv[tl][hf][2 * p + 1]));
                        }
                }
            }
            // publish right strip (cols l0+7..l0+15, read by right neighbor)
            {
                int cs = -1, tr_ = 0;
                if (l16 == 15)     { cs = 0;        tr_ = 0; }
                else if (l16 <= 7) { cs = l16 + 1;  tr_ = 1; }
                if (cs >= 0 && lw < 7) {
                    u64* mp = mbox + (((long)(b * 8 + lw) * 2 + 1) * 2 + par) * 1152 + cs * 128;
#pragma unroll
                    for (int hf = 0; hf < 2; ++hf)
#pragma unroll
                        for (int p = 0; p < 2; ++p) {
                            int hp = wid * 16 + hf * 8 + g * 2 + p;
                            st_mb(mp + hp, tagw |
                                  (u64)pack_h2(hv[tr_][hf][2 * p], hv[tr_][hf][2 * p + 1]));
                        }
                }
            }
            // poll + refill margins: rows 0..8 <- left nb right-strip; rows 25..33 <- right nb left-strip
            for (int i = tid; i < 2304; i += 512) {
                int side = (i >= 1152);
                int j = i - side * 1152;
                int col = j >> 7, hp = j & 127;
                int nb = lw + (side ? 1 : -1);
                if ((unsigned)nb < 8u) {
                    const u64* p = mbox + (((long)(b * 8 + nb) * 2 + (side ? 0 : 1)) * 2 + par) * 1152 + j;
                    u64 v = ld_mb(p);
                    while ((unsigned)(v >> 32) < e) {
                        __builtin_amdgcn_s_sleep(1);
                        v = ld_mb(p);
                    }
                    unsigned pk = (unsigned)v;
                    int row = side ? 25 + col : col;
                    int c = hp * 2;
                    int off = row * 512 + ((((c >> 3) ^ (row & 7)) << 4)) + (c & 7) * 2;
                    f16x2 w; __builtin_memcpy(&w, &pk, 4);
                    *(f16x2*)(smem + off) = w;
                }
            }
            __syncthreads();   // margins refreshed before next step's h-conv
        }
    }
}

extern "C" void kernel_launch(void* const* d_in, const int* in_sizes, int n_in,
                              void* d_out, int out_size, void* d_ws, size_t ws_size,
                              hipStream_t stream)
{
    const float* x   = (const float*)d_in[0];   // [16][64][128][128]
    const float* W_i = (const float*)d_in[1];   // [256][128][3]
    const float* W_h = (const float*)d_in[2];   // [256][256][3]
    float* out = (float*)d_out;                 // [16][64][256][128]

    f16* wt_i = (f16*)d_ws;                              // 196608 B
    f16* wt_h = (f16*)((char*)d_ws + 196608);            // 393216 B
    u64* mbox = (u64*)((char*)d_ws + 589824);            // 16*8*2*2*1152*8 = 4718592 B

    prep_w<<<1152, 256, 0, stream>>>(W_i, wt_i, W_h, wt_h);
    hipMemsetAsync(mbox, 0, 4718592, stream);            // tags <- 0

    rnn_fused<<<128, 512, 0, stream>>>(x, wt_i, wt_h, out, mbox);
}